// Round 3
// baseline (934.146 us; speedup 1.0000x reference)
//
#include <hip/hip_runtime.h>
#include <stdint.h>
#include <stddef.h>

typedef __attribute__((ext_vector_type(8))) short short8;
typedef __attribute__((ext_vector_type(4))) float f32x4;

#define NB 8
#define NC 384
#define HH 256
#define WW 256
#define PR 264                      // padded row stride (bf16 elems)
#define PROWS 264                   // padded rows allocated
#define PLANE (PR * PROWS)          // 69696
#define IMG_ELEMS (NB * PLANE)      // 557568 (= 2178*256 exactly)
#define IMG_BLOCKS 2178
#define NFRAG 3072                  // 24 ct * 2 kc * 64 lanes
#define EXTRA_BLOCKS 14             // ceil((3072+384)/256)
#define PREP_BLOCKS (IMG_BLOCKS + EXTRA_BLOCKS)

#define GRID 1024
#define ITERS 32                    // 1024*32 = 32768 = 8b * 256h * 16 w-tiles

__device__ __forceinline__ unsigned short f2bf(float f) {
    unsigned int u = __float_as_uint(f);
    return (unsigned short)((u + 0x7FFFu + ((u >> 16) & 1u)) >> 16);
}

// Builds: (1) zero-padded bf16 image tjp[8][264][264] (+3 halo, rows/cols >258 zero)
//         (2) weight fragments: slot(ct,kc,lane,j): ch=ct*16+(lane&15),
//             kh=kc*4+(lane>>4), kw=j, zero if kh>=7 or j>=7
//         (3) bias[c] = 1 - D_i[0][c] - B[c]
__global__ __launch_bounds__(256) void prep_kernel(
    const float* __restrict__ tj, const float* __restrict__ kern,
    const float* __restrict__ Bv, const float* __restrict__ Di,
    unsigned short* __restrict__ tjp, unsigned short* __restrict__ wfrag,
    float* __restrict__ bias)
{
    int bid = blockIdx.x, tid = threadIdx.x;
    if (bid < IMG_BLOCKS) {
        int idx = bid * 256 + tid;          // always < IMG_ELEMS (exact fit)
        int b = idx / PLANE;
        int rem = idx - b * PLANE;
        int r = rem / PR;
        int c = rem - r * PR;
        int hh = r - 3, ww = c - 3;
        float v = 0.f;
        if (hh >= 0 && hh < HH && ww >= 0 && ww < WW)
            v = tj[(b * HH + hh) * WW + ww];
        tjp[idx] = f2bf(v);
    } else {
        int idx = (bid - IMG_BLOCKS) * 256 + tid;
        if (idx < NFRAG) {
            int lane = idx & 63;
            int fk = idx >> 6;              // ct*2 + kc
            int kc = fk & 1, ct = fk >> 1;
            int ch = ct * 16 + (lane & 15);
            int kh = kc * 4 + (lane >> 4);
            unsigned int tmp[8];
            #pragma unroll
            for (int j = 0; j < 8; ++j) {
                float v = 0.f;
                if (kh < 7 && j < 7) v = kern[(ch * 7 + kh) * 7 + j];
                tmp[j] = f2bf(v);
            }
            uint4 pk;
            pk.x = tmp[0] | (tmp[1] << 16);
            pk.y = tmp[2] | (tmp[3] << 16);
            pk.z = tmp[4] | (tmp[5] << 16);
            pk.w = tmp[6] | (tmp[7] << 16);
            ((uint4*)wfrag)[idx] = pk;
        } else if (idx < NFRAG + NC) {
            int c = idx - NFRAG;
            bias[c] = 1.0f - Di[c] - Bv[c];
        }
    }
}

// Each wave: one w-tile (16 w) x 96 channels (6 ct), weights+bias in registers.
// Block of 4 waves covers all 384 channels of one w-tile per iteration.
__global__ __launch_bounds__(256, 2) void conv_main(
    const unsigned short* __restrict__ tjp,
    const unsigned short* __restrict__ wfrag,
    const float* __restrict__ bias,
    float* __restrict__ out)
{
    int tid = threadIdx.x;
    int wave = tid >> 6, lane = tid & 63;
    int q = lane >> 4, n = lane & 15;
    int ct0 = wave * 6;

    // Preload A-fragments (weights) and bias into registers
    short8 wf[12];
    const short8* wp = (const short8*)wfrag;
    #pragma unroll
    for (int i = 0; i < 12; ++i)
        wf[i] = wp[(ct0 * 2 + i) * 64 + lane];

    float bv[24];
    #pragma unroll
    for (int t = 0; t < 24; ++t) {
        int ct = t >> 2, reg = t & 3;
        bv[t] = bias[(ct0 + ct) * 16 + q * 4 + reg];
    }

    for (int t = 0; t < ITERS; ++t) {
        int i = blockIdx.x * ITERS + t;
        int wt = i & 15;
        int h  = (i >> 4) & 255;
        int b  = i >> 12;
        int w0 = wt * 16;

        // B-fragments: lane's 8 elems = taps (kh = kc*4+q, kw = 0..7) applied at
        // output col w0+n -> 8 contiguous bf16 of padded row h+kh, start w0+n.
        const unsigned short* src = tjp + b * PLANE + (h + q) * PR + w0 + n;
        short8 pb0, pb1;
        __builtin_memcpy(&pb0, src, 16);            // kh = q      (0..3)
        __builtin_memcpy(&pb1, src + 4 * PR, 16);   // kh = 4 + q  (4..7, 7 is zero-weight)

        #pragma unroll
        for (int ct = 0; ct < 6; ++ct) {
            f32x4 acc = {0.f, 0.f, 0.f, 0.f};
            acc = __builtin_amdgcn_mfma_f32_16x16x32_bf16(wf[ct * 2 + 0], pb0, acc, 0, 0, 0);
            acc = __builtin_amdgcn_mfma_f32_16x16x32_bf16(wf[ct * 2 + 1], pb1, acc, 0, 0, 0);
            // D layout: lane holds D[m = 4q+reg][n], channel = (ct0+ct)*16 + 4q + reg
            size_t base = ((size_t)(b * NC + (ct0 + ct) * 16 + q * 4) << 16)
                        + ((size_t)h << 8) + (size_t)(w0 + n);
            #pragma unroll
            for (int reg = 0; reg < 4; ++reg) {
                float v = acc[reg] + bv[ct * 4 + reg];
                v = fminf(v, 1.0f);
                out[base + ((size_t)reg << 16)] = v;
            }
        }
    }
}

extern "C" void kernel_launch(void* const* d_in, const int* in_sizes, int n_in,
                              void* d_out, int out_size, void* d_ws, size_t ws_size,
                              hipStream_t stream) {
    (void)in_sizes; (void)n_in; (void)out_size; (void)ws_size;
    const float* tj   = (const float*)d_in[0];
    const float* kern = (const float*)d_in[1];
    const float* Bv   = (const float*)d_in[2];
    const float* Di   = (const float*)d_in[3];
    float* out = (float*)d_out;

    // workspace layout
    unsigned short* tjp   = (unsigned short*)d_ws;                   // 1,115,136 B
    unsigned short* wfrag = (unsigned short*)((char*)d_ws + (size_t)IMG_ELEMS * 2);   // 49,152 B (16B aligned)
    float* bias           = (float*)((char*)d_ws + (size_t)IMG_ELEMS * 2 + NFRAG * 16);

    prep_kernel<<<PREP_BLOCKS, 256, 0, stream>>>(tj, kern, Bv, Di, tjp, wfrag, bias);
    conv_main<<<GRID, 256, 0, stream>>>(tjp, wfrag, bias, out);
}

// Round 4
// 909.798 us; speedup vs baseline: 1.0268x; 1.0268x over previous
//
#include <hip/hip_runtime.h>
#include <stdint.h>
#include <stddef.h>

typedef __attribute__((ext_vector_type(8))) short short8;
typedef __attribute__((ext_vector_type(4))) float f32x4;

#define NB 8
#define NC 384
#define HH 256
#define WW 256
#define PR 264                      // padded row stride (bf16 elems)
#define PROWS 264                   // padded rows allocated
#define PLANE (PR * PROWS)          // 69696
#define IMG_ELEMS (NB * PLANE)      // 557568 (= 2178*256 exactly)
#define IMG_BLOCKS 2178
#define NFRAG 3072                  // 24 ct * 2 kc * 64 lanes
#define EXTRA_BLOCKS 14             // ceil((3072+384)/256)
#define PREP_BLOCKS (IMG_BLOCKS + EXTRA_BLOCKS)

#define GRID 4096
#define ITERS 8                     // 4096*8 = 32768 = 8b * 256h * 16 w-tiles

__device__ __forceinline__ unsigned short f2bf(float f) {
    unsigned int u = __float_as_uint(f);
    return (unsigned short)((u + 0x7FFFu + ((u >> 16) & 1u)) >> 16);
}

// Builds: (1) zero-padded bf16 image tjp[8][264][264] (+3 halo, rows/cols >258 zero)
//         (2) weight fragments: slot(ct,kc,lane,j): ch=ct*16+(lane&15),
//             kh=kc*4+(lane>>4), kw=j, zero if kh>=7 or j>=7
//         (3) bias[c] = 1 - D_i[0][c] - B[c]
__global__ __launch_bounds__(256) void prep_kernel(
    const float* __restrict__ tj, const float* __restrict__ kern,
    const float* __restrict__ Bv, const float* __restrict__ Di,
    unsigned short* __restrict__ tjp, unsigned short* __restrict__ wfrag,
    float* __restrict__ bias)
{
    int bid = blockIdx.x, tid = threadIdx.x;
    if (bid < IMG_BLOCKS) {
        int idx = bid * 256 + tid;          // always < IMG_ELEMS (exact fit)
        int b = idx / PLANE;
        int rem = idx - b * PLANE;
        int r = rem / PR;
        int c = rem - r * PR;
        int hh = r - 3, ww = c - 3;
        float v = 0.f;
        if (hh >= 0 && hh < HH && ww >= 0 && ww < WW)
            v = tj[(b * HH + hh) * WW + ww];
        tjp[idx] = f2bf(v);
    } else {
        int idx = (bid - IMG_BLOCKS) * 256 + tid;
        if (idx < NFRAG) {
            int lane = idx & 63;
            int fk = idx >> 6;              // ct*2 + kc
            int kc = fk & 1, ct = fk >> 1;
            int ch = ct * 16 + (lane & 15);
            int kh = kc * 4 + (lane >> 4);
            unsigned int tmp[8];
            #pragma unroll
            for (int j = 0; j < 8; ++j) {
                float v = 0.f;
                if (kh < 7 && j < 7) v = kern[(ch * 7 + kh) * 7 + j];
                tmp[j] = f2bf(v);
            }
            uint4 pk;
            pk.x = tmp[0] | (tmp[1] << 16);
            pk.y = tmp[2] | (tmp[3] << 16);
            pk.z = tmp[4] | (tmp[5] << 16);
            pk.w = tmp[6] | (tmp[7] << 16);
            ((uint4*)wfrag)[idx] = pk;
        } else if (idx < NFRAG + NC) {
            int c = idx - NFRAG;
            bias[c] = 1.0f - Di[c] - Bv[c];
        }
    }
}

// 8 waves per block; each wave owns 48 channels (3 ct) of one w-tile per iter.
// Low register footprint (~60 VGPR) -> 3 blocks/CU (24 waves/CU), no spills.
__global__ __launch_bounds__(512, 6) void conv_main(
    const unsigned short* __restrict__ tjp,
    const unsigned short* __restrict__ wfrag,
    const float* __restrict__ bias,
    float* __restrict__ out)
{
    int tid = threadIdx.x;
    int wave = tid >> 6, lane = tid & 63;
    int q = lane >> 4, n = lane & 15;
    int ct0 = wave * 3;

    // Preload A-fragments (weights) and bias into registers
    short8 wf[6];
    const short8* wp = (const short8*)wfrag;
    #pragma unroll
    for (int i = 0; i < 6; ++i)
        wf[i] = wp[(ct0 * 2 + i) * 64 + lane];

    float bv[12];
    #pragma unroll
    for (int t = 0; t < 12; ++t) {
        int ct = t >> 2, reg = t & 3;
        bv[t] = bias[(ct0 + ct) * 16 + q * 4 + reg];
    }

    for (int t = 0; t < ITERS; ++t) {
        int i = blockIdx.x * ITERS + t;
        int wt = i & 15;
        int h  = (i >> 4) & 255;
        int b  = i >> 12;
        int w0 = wt * 16;

        // B-fragments: lane's 8 elems = taps (kh = kc*4+q, kw = 0..7) applied at
        // output col w0+n -> 8 contiguous bf16 of padded row h+kh, start w0+n.
        const unsigned short* src = tjp + b * PLANE + (h + q) * PR + w0 + n;
        short8 pb0, pb1;
        __builtin_memcpy(&pb0, src, 16);            // kh = q      (0..3)
        __builtin_memcpy(&pb1, src + 4 * PR, 16);   // kh = 4 + q  (4..7, 7 is zero-weight)

        // 32-bit float-index base (out < 2^29 bytes): saddr + voffset stores
        unsigned int base0 = ((unsigned int)(b * NC + ct0 * 16 + q * 4) << 16)
                           + ((unsigned int)h << 8) + (unsigned int)(w0 + n);
        #pragma unroll
        for (int ct = 0; ct < 3; ++ct) {
            f32x4 acc = {0.f, 0.f, 0.f, 0.f};
            acc = __builtin_amdgcn_mfma_f32_16x16x32_bf16(wf[ct * 2 + 0], pb0, acc, 0, 0, 0);
            acc = __builtin_amdgcn_mfma_f32_16x16x32_bf16(wf[ct * 2 + 1], pb1, acc, 0, 0, 0);
            unsigned int base = base0 + ((unsigned int)ct << 20);   // +16 channels
            #pragma unroll
            for (int reg = 0; reg < 4; ++reg) {
                float v = acc[reg] + bv[ct * 4 + reg];
                v = fminf(v, 1.0f);
                out[base + ((unsigned int)reg << 16)] = v;
            }
        }
    }
}

extern "C" void kernel_launch(void* const* d_in, const int* in_sizes, int n_in,
                              void* d_out, int out_size, void* d_ws, size_t ws_size,
                              hipStream_t stream) {
    (void)in_sizes; (void)n_in; (void)out_size; (void)ws_size;
    const float* tj   = (const float*)d_in[0];
    const float* kern = (const float*)d_in[1];
    const float* Bv   = (const float*)d_in[2];
    const float* Di   = (const float*)d_in[3];
    float* out = (float*)d_out;

    // workspace layout
    unsigned short* tjp   = (unsigned short*)d_ws;                   // 1,115,136 B
    unsigned short* wfrag = (unsigned short*)((char*)d_ws + (size_t)IMG_ELEMS * 2);   // 49,152 B (16B aligned)
    float* bias           = (float*)((char*)d_ws + (size_t)IMG_ELEMS * 2 + NFRAG * 16);

    prep_kernel<<<PREP_BLOCKS, 256, 0, stream>>>(tj, kern, Bv, Di, tjp, wfrag, bias);
    conv_main<<<GRID, 512, 0, stream>>>(tjp, wfrag, bias, out);
}

// Round 5
// 833.293 us; speedup vs baseline: 1.1210x; 1.0918x over previous
//
#include <hip/hip_runtime.h>
#include <stdint.h>
#include <stddef.h>

typedef __attribute__((ext_vector_type(8))) short short8;
typedef __attribute__((ext_vector_type(4))) float f32x4;
typedef __attribute__((ext_vector_type(4))) unsigned int uint4v;

// 16B vector load with only 4B alignment guarantee (odd-ushort start)
struct __attribute__((packed, aligned(4))) u4a4 { uint4v v; };

#define NB 8
#define NC 384
#define HH 256
#define WW 256
#define PR 264                      // padded row stride (bf16 elems)
#define PROWS 264
#define PLANE (PR * PROWS)          // 69696
#define IMG_ELEMS (NB * PLANE)      // 557568 (= 2178*256 exactly)
#define IMG_BLOCKS 2178
#define NFRAG 3072                  // 24 ct * 2 kc * 64 lanes
#define EXTRA_BLOCKS 14
#define PREP_BLOCKS (IMG_BLOCKS + EXTRA_BLOCKS)

#define GRID 3072                   // 8 b * 24 ct * 16 h-chunks
#define HITERS 16

__device__ __forceinline__ unsigned short f2bf(float f) {
    unsigned int u = __float_as_uint(f);
    return (unsigned short)((u + 0x7FFFu + ((u >> 16) & 1u)) >> 16);
}

__device__ __forceinline__ float padval(const float* __restrict__ tj, int idx) {
    int b = idx / PLANE;
    int rem = idx - b * PLANE;
    int r = rem / PR;
    int c = rem - r * PR;
    int hh = r - 3, ww = c - 3;
    if (b < NB && hh >= 0 && hh < HH && ww >= 0 && ww < WW)
        return tj[(b * HH + hh) * WW + ww];
    return 0.f;
}

__device__ __forceinline__ short8 ld16a4(const void* p) {
    union { uint4v u; short8 s; } cv;
    cv.u = ((const u4a4*)p)->v;
    return cv.s;
}

// Builds: (1) even padded bf16 image tjp_e[idx] = pad(idx); odd copy tjp_o[idx] = pad(idx+1)
//         (2) weight fragments: slot(ct,kc,lane,j): ch=ct*16+(lane&15), kh=kc*4+(lane>>4), kw=j
//         (3) bias[c] = 1 - D_i[0][c] - B[c]
__global__ __launch_bounds__(256) void prep_kernel(
    const float* __restrict__ tj, const float* __restrict__ kern,
    const float* __restrict__ Bv, const float* __restrict__ Di,
    unsigned short* __restrict__ tjp_e, unsigned short* __restrict__ tjp_o,
    unsigned short* __restrict__ wfrag, float* __restrict__ bias)
{
    int bid = blockIdx.x, tid = threadIdx.x;
    if (bid < IMG_BLOCKS) {
        int idx = bid * 256 + tid;          // < IMG_ELEMS (exact fit)
        tjp_e[idx] = f2bf(padval(tj, idx));
        tjp_o[idx] = f2bf((idx + 1 < IMG_ELEMS) ? padval(tj, idx + 1) : 0.f);
    } else {
        int idx = (bid - IMG_BLOCKS) * 256 + tid;
        if (idx < NFRAG) {
            int lane = idx & 63;
            int fk = idx >> 6;              // ct*2 + kc
            int kc = fk & 1, ct = fk >> 1;
            int ch = ct * 16 + (lane & 15);
            int kh = kc * 4 + (lane >> 4);
            unsigned int tmp[8];
            #pragma unroll
            for (int j = 0; j < 8; ++j) {
                float v = 0.f;
                if (kh < 7 && j < 7) v = kern[(ch * 7 + kh) * 7 + j];
                tmp[j] = f2bf(v);
            }
            uint4 pk;
            pk.x = tmp[0] | (tmp[1] << 16);
            pk.y = tmp[2] | (tmp[3] << 16);
            pk.z = tmp[4] | (tmp[5] << 16);
            pk.w = tmp[6] | (tmp[7] << 16);
            ((uint4*)wfrag)[idx] = pk;
        } else if (idx < NFRAG + NC) {
            int c = idx - NFRAG;
            bias[c] = 1.0f - Di[c] - Bv[c];
        }
    }
}

// Block = (b, ct: 16 channels, hc: 16 rows). 8 waves tile the full 256-w row
// (2 w-tiles each). MFMA: A = patches (M=16 w), B = weights (N=16 ch) ->
// lane holds 4 consecutive w for one channel -> dwordx4 stores; per h-iter the
// block writes 16 planes x 1KB contiguous, h sequential (DRAM row locality).
__global__ __launch_bounds__(512, 6) void conv_main(
    const unsigned short* __restrict__ tjp_e,
    const unsigned short* __restrict__ tjp_o,
    const unsigned short* __restrict__ wfrag,
    const float* __restrict__ bias,
    float* __restrict__ out)
{
    int tid = threadIdx.x;
    int wave = tid >> 6, lane = tid & 63;
    int q = lane >> 4, n = lane & 15;

    int bid = blockIdx.x;
    int b  = bid / 384;
    int r1 = bid - b * 384;
    int ct = r1 >> 4;
    int hc = r1 & 15;

    // B operand: weights (col = channel = lane&15)
    const short8* wp = (const short8*)wfrag;
    short8 wf0 = wp[(ct * 2 + 0) * 64 + lane];
    short8 wf1 = wp[(ct * 2 + 1) * 64 + lane];
    float bv = bias[ct * 16 + n];

    // parity-selected image base: element e read at base + 2*e, 4B-aligned
    const char* base = (n & 1) ? ((const char*)tjp_o - 2) : (const char*)tjp_e;

    int w0 = wave * 32;                     // this wave's 32-w span
    unsigned int obase = ((unsigned int)(b * NC + ct * 16 + n) << 16) + (unsigned int)(w0 + 4 * q);

    for (int t = 0; t < HITERS; ++t) {
        int h = hc * HITERS + t;
        unsigned int e = (unsigned int)(b * PLANE + (h + q) * PR + w0 + n);
        const char* p = base + 2u * e;

        short8 a00 = ld16a4(p);                     // tile0, rows h+q   (kh=q)
        short8 a01 = ld16a4(p + 8 * PR);            // tile0, rows h+4+q (kh=4+q)
        short8 a10 = ld16a4(p + 32);                // tile1 (+16 w)
        short8 a11 = ld16a4(p + 32 + 8 * PR);

        f32x4 acc0 = {0.f, 0.f, 0.f, 0.f};
        f32x4 acc1 = {0.f, 0.f, 0.f, 0.f};
        acc0 = __builtin_amdgcn_mfma_f32_16x16x32_bf16(a00, wf0, acc0, 0, 0, 0);
        acc0 = __builtin_amdgcn_mfma_f32_16x16x32_bf16(a01, wf1, acc0, 0, 0, 0);
        acc1 = __builtin_amdgcn_mfma_f32_16x16x32_bf16(a10, wf0, acc1, 0, 0, 0);
        acc1 = __builtin_amdgcn_mfma_f32_16x16x32_bf16(a11, wf1, acc1, 0, 0, 0);

        f32x4 r0, r1v;
        #pragma unroll
        for (int reg = 0; reg < 4; ++reg) {
            r0[reg]  = fminf(acc0[reg] + bv, 1.0f);
            r1v[reg] = fminf(acc1[reg] + bv, 1.0f);
        }
        unsigned int o = obase + ((unsigned int)h << 8);
        *(f32x4*)(out + o)      = r0;      // w0+4q .. +3      (16B aligned)
        *(f32x4*)(out + o + 16) = r1v;     // w0+16+4q .. +3
    }
}

extern "C" void kernel_launch(void* const* d_in, const int* in_sizes, int n_in,
                              void* d_out, int out_size, void* d_ws, size_t ws_size,
                              hipStream_t stream) {
    (void)in_sizes; (void)n_in; (void)out_size; (void)ws_size;
    const float* tj   = (const float*)d_in[0];
    const float* kern = (const float*)d_in[1];
    const float* Bv   = (const float*)d_in[2];
    const float* Di   = (const float*)d_in[3];
    float* out = (float*)d_out;

    // workspace layout
    char* ws = (char*)d_ws;
    unsigned short* tjp_e = (unsigned short*)ws;                                  // 1,115,136 B
    unsigned short* tjp_o = (unsigned short*)(ws + (size_t)IMG_ELEMS * 2);        // 1,115,136 B
    unsigned short* wfrag = (unsigned short*)(ws + (size_t)IMG_ELEMS * 4);        // 49,152 B
    float* bias           = (float*)(ws + (size_t)IMG_ELEMS * 4 + NFRAG * 16);    // 1,536 B

    prep_kernel<<<PREP_BLOCKS, 256, 0, stream>>>(tj, kern, Bv, Di, tjp_e, tjp_o, wfrag, bias);
    conv_main<<<GRID, 512, 0, stream>>>(tjp_e, tjp_o, wfrag, bias, out);
}